// Round 1
// baseline (540.859 us; speedup 1.0000x reference)
//
#include <hip/hip_runtime.h>
#include <stdint.h>

#define QMAXF 127.0f

constexpr int Mdim = 8192;
constexpr int Kdim = 4096;
constexpr int Ndim = 4096;

using i32x4 = __attribute__((ext_vector_type(4))) int;

__device__ __forceinline__ void async_copy16(const void* g, void* l) {
    __builtin_amdgcn_global_load_lds(
        (const __attribute__((address_space(1))) void*)g,
        (__attribute__((address_space(3))) void*)l,
        16, 0, 0);
}

__global__ void zero_scalar_kernel(unsigned* p) { *p = 0u; }

__global__ void absmax_kernel(const float* __restrict__ x,
                              unsigned* __restrict__ out, int n4) {
    float m = 0.f;
    const float4* x4 = (const float4*)x;
    for (int i = blockIdx.x * blockDim.x + threadIdx.x; i < n4;
         i += gridDim.x * blockDim.x) {
        float4 v = x4[i];
        m = fmaxf(m, fmaxf(fmaxf(fabsf(v.x), fabsf(v.y)),
                           fmaxf(fabsf(v.z), fabsf(v.w))));
    }
#pragma unroll
    for (int off = 32; off > 0; off >>= 1)
        m = fmaxf(m, __shfl_down(m, off, 64));
    if ((threadIdx.x & 63) == 0)
        atomicMax(out, __float_as_uint(m));  // non-negative floats: bit order == value order
}

__global__ void quant_x_kernel(const float* __restrict__ x,
                               const unsigned* __restrict__ maxbits,
                               int8_t* __restrict__ xq, int n4) {
    const float s = __uint_as_float(*maxbits) / QMAXF;
    const float4* x4 = (const float4*)x;
    char4* q4 = (char4*)xq;
    for (int i = blockIdx.x * blockDim.x + threadIdx.x; i < n4;
         i += gridDim.x * blockDim.x) {
        float4 v = x4[i];
        char4 q;
        // precise division + rintf matches jnp round(x / s_x) (round-half-even)
        q.x = (signed char)(int)fminf(QMAXF, fmaxf(-QMAXF, rintf(v.x / s)));
        q.y = (signed char)(int)fminf(QMAXF, fmaxf(-QMAXF, rintf(v.y / s)));
        q.z = (signed char)(int)fminf(QMAXF, fmaxf(-QMAXF, rintf(v.z / s)));
        q.w = (signed char)(int)fminf(QMAXF, fmaxf(-QMAXF, rintf(v.w / s)));
        q4[i] = q;
    }
}

__global__ void conv_w_kernel(const int* __restrict__ w32,
                              int8_t* __restrict__ w8, int n4) {
    const int4* in4 = (const int4*)w32;
    char4* out4 = (char4*)w8;
    for (int i = blockIdx.x * blockDim.x + threadIdx.x; i < n4;
         i += gridDim.x * blockDim.x) {
        int4 v = in4[i];
        char4 c;
        c.x = (signed char)v.x;
        c.y = (signed char)v.y;
        c.z = (signed char)v.z;
        c.w = (signed char)v.w;
        out4[i] = c;
    }
}

// ---------------------------------------------------------------------------
// int8 GEMM: C[M,N] = Xq[M,K] . Wq[N,K]^T   (both K-major => m97 gemm_bt shape)
// 128x128 tile / block, 4 waves, each wave 64x64 via 4x4 grid of 16x16x64 MFMA.
// BK=64 bytes per row; LDS 2 x 8KB; global_load_lds width=16; 2-barrier K-loop.
// ---------------------------------------------------------------------------
#define BM 128
#define BN 128
#define BK 64

__global__ __launch_bounds__(256) void gemm_i8_kernel(
    const int8_t* __restrict__ Xq, const int8_t* __restrict__ Wq,
    const unsigned* __restrict__ maxbits, const float* __restrict__ s_w,
    const float* __restrict__ bias, float* __restrict__ Y) {
    __shared__ int8_t As[BM * BK];
    __shared__ int8_t Bs[BN * BK];

    const int t = threadIdx.x;
    const int w = t >> 6;
    const int l = t & 63;
    const int lane15 = l & 15;
    const int lquad = l >> 4;
    const int wm = (w >> 1) * 64;  // wave's row quadrant within tile
    const int wn = (w & 1) * 64;   // wave's col quadrant within tile

    const int bm = blockIdx.y * BM;
    const int bn = blockIdx.x * BN;

    // staging: 512 chunks of 16B per 8KB tile; thread t does chunks t and 256+t
    const int c0 = t;
    const int c1 = 256 + t;
    const int rA0 = c0 >> 2, kA0 = (c0 & 3) * 16;
    const int rA1 = c1 >> 2, kA1 = (c1 & 3) * 16;

    const int8_t* aptr0 = Xq + (size_t)(bm + rA0) * Kdim + kA0;
    const int8_t* aptr1 = Xq + (size_t)(bm + rA1) * Kdim + kA1;
    const int8_t* bptr0 = Wq + (size_t)(bn + rA0) * Kdim + kA0;
    const int8_t* bptr1 = Wq + (size_t)(bn + rA1) * Kdim + kA1;

    // wave-uniform LDS bases (HW scatters lane l at base + l*16)
    int8_t* asw0 = As + w * 1024;
    int8_t* asw1 = As + 4096 + w * 1024;
    int8_t* bsw0 = Bs + w * 1024;
    int8_t* bsw1 = Bs + 4096 + w * 1024;

    i32x4 acc[4][4] = {};

    for (int kt = 0; kt < Kdim; kt += BK) {
        async_copy16(aptr0 + kt, asw0);
        async_copy16(aptr1 + kt, asw1);
        async_copy16(bptr0 + kt, bsw0);
        async_copy16(bptr1 + kt, bsw1);
        __syncthreads();  // drains vmcnt(0): LDS tiles valid for all waves

        i32x4 a[4], b[4];
#pragma unroll
        for (int i = 0; i < 4; i++)
            a[i] = *(const i32x4*)(As + (wm + i * 16 + lane15) * BK + lquad * 16);
#pragma unroll
        for (int j = 0; j < 4; j++)
            b[j] = *(const i32x4*)(Bs + (wn + j * 16 + lane15) * BK + lquad * 16);

#pragma unroll
        for (int i = 0; i < 4; i++)
#pragma unroll
            for (int j = 0; j < 4; j++)
                acc[i][j] = __builtin_amdgcn_mfma_i32_16x16x64_i8(
                    a[i], b[j], acc[i][j], 0, 0, 0);

        __syncthreads();  // all waves done reading before next overwrite
    }

    // epilogue: C/D layout col=lane&15, row=(lane>>4)*4+reg (16x16 shapes)
    const float sx = __uint_as_float(*maxbits) / QMAXF;
#pragma unroll
    for (int j = 0; j < 4; j++) {
        const int col = bn + wn + j * 16 + lane15;
        const float sc = sx * s_w[col];
        const float bs = bias[col];
#pragma unroll
        for (int i = 0; i < 4; i++) {
            const int row = bm + wm + i * 16 + lquad * 4;
            float* yp = Y + (size_t)row * Ndim + col;
#pragma unroll
            for (int r = 0; r < 4; r++)
                yp[(size_t)r * Ndim] = (float)acc[i][j][r] * sc + bs;
        }
    }
}

extern "C" void kernel_launch(void* const* d_in, const int* in_sizes, int n_in,
                              void* d_out, int out_size, void* d_ws,
                              size_t ws_size, hipStream_t stream) {
    const float* x = (const float*)d_in[0];
    const int* w_q = (const int*)d_in[1];   // integer inputs arrive as int32
    const float* s_w = (const float*)d_in[2];
    const float* bias = (const float*)d_in[3];
    float* y = (float*)d_out;

    unsigned* maxbits = (unsigned*)d_ws;
    int8_t* xq = (int8_t*)d_ws + 256;
    int8_t* wq8 = (int8_t*)d_ws + 256 + (size_t)Mdim * Kdim;

    zero_scalar_kernel<<<1, 1, 0, stream>>>(maxbits);
    absmax_kernel<<<2048, 256, 0, stream>>>(x, maxbits, Mdim * Kdim / 4);
    quant_x_kernel<<<2048, 256, 0, stream>>>(x, maxbits, xq, Mdim * Kdim / 4);
    conv_w_kernel<<<2048, 256, 0, stream>>>(w_q, wq8, Ndim * Kdim / 4);

    dim3 grid(Ndim / BN, Mdim / BM);
    gemm_i8_kernel<<<grid, 256, 0, stream>>>(xq, wq8, maxbits, s_w, bias, y);
}

// Round 2
// 431.928 us; speedup vs baseline: 1.2522x; 1.2522x over previous
//
#include <hip/hip_runtime.h>
#include <stdint.h>

#define QMAXF 127.0f

constexpr int Mdim = 8192;
constexpr int Kdim = 4096;
constexpr int Ndim = 4096;
constexpr int PREP_BLOCKS = 2048;

using i32x4 = __attribute__((ext_vector_type(4))) int;

__device__ __forceinline__ void async_copy16(const void* g, void* l) {
    __builtin_amdgcn_global_load_lds(
        (const __attribute__((address_space(1))) void*)g,
        (__attribute__((address_space(3))) void*)l,
        16, 0, 0);
}

// ---------------------------------------------------------------------------
// Pass 1: per-block |x| maxima (plain stores, NO atomics) + w int32->int8.
// ---------------------------------------------------------------------------
__global__ void prep_kernel(const float* __restrict__ x,
                            const int* __restrict__ w32,
                            float* __restrict__ blockmax,
                            int8_t* __restrict__ w8) {
    float m = 0.f;
    const float4* x4 = (const float4*)x;
    const int n4x = Mdim * Kdim / 4;
    for (int i = blockIdx.x * blockDim.x + threadIdx.x; i < n4x;
         i += gridDim.x * blockDim.x) {
        float4 v = x4[i];
        m = fmaxf(fmaxf(fabsf(v.x), fabsf(v.y)),
                  fmaxf(m, fmaxf(fabsf(v.z), fabsf(v.w))));
    }
#pragma unroll
    for (int off = 32; off > 0; off >>= 1)
        m = fmaxf(m, __shfl_down(m, off, 64));
    __shared__ float red[4];
    if ((threadIdx.x & 63) == 0) red[threadIdx.x >> 6] = m;
    __syncthreads();
    if (threadIdx.x == 0)
        blockmax[blockIdx.x] =
            fmaxf(fmaxf(red[0], red[1]), fmaxf(red[2], red[3]));

    // fused: narrow w (independent of the reduction above)
    const int4* in4 = (const int4*)w32;
    char4* out4 = (char4*)w8;
    const int n4w = Ndim * Kdim / 4;
    for (int i = blockIdx.x * blockDim.x + threadIdx.x; i < n4w;
         i += gridDim.x * blockDim.x) {
        int4 v = in4[i];
        char4 c;
        c.x = (signed char)v.x;
        c.y = (signed char)v.y;
        c.z = (signed char)v.z;
        c.w = (signed char)v.w;
        out4[i] = c;
    }
}

// Pass 2: reduce 2048 block maxima -> s_x = max/127 (one block, ~3 us)
__global__ void finalize_kernel(const float* __restrict__ blockmax,
                                float* __restrict__ sx) {
    float m = 0.f;
    for (int i = threadIdx.x; i < PREP_BLOCKS; i += 256)
        m = fmaxf(m, blockmax[i]);
#pragma unroll
    for (int off = 32; off > 0; off >>= 1)
        m = fmaxf(m, __shfl_down(m, off, 64));
    __shared__ float red[4];
    if ((threadIdx.x & 63) == 0) red[threadIdx.x >> 6] = m;
    __syncthreads();
    if (threadIdx.x == 0)
        *sx = fmaxf(fmaxf(red[0], red[1]), fmaxf(red[2], red[3])) / QMAXF;
}

// Pass 3: quantize x -> int8 with the (now known) scalar scale
__global__ void quant_x_kernel(const float* __restrict__ x,
                               const float* __restrict__ sxp,
                               int8_t* __restrict__ xq, int n4) {
    const float s = *sxp;
    const float4* x4 = (const float4*)x;
    char4* q4 = (char4*)xq;
    for (int i = blockIdx.x * blockDim.x + threadIdx.x; i < n4;
         i += gridDim.x * blockDim.x) {
        float4 v = x4[i];
        char4 q;
        q.x = (signed char)(int)fminf(QMAXF, fmaxf(-QMAXF, rintf(v.x / s)));
        q.y = (signed char)(int)fminf(QMAXF, fmaxf(-QMAXF, rintf(v.y / s)));
        q.z = (signed char)(int)fminf(QMAXF, fmaxf(-QMAXF, rintf(v.z / s)));
        q.w = (signed char)(int)fminf(QMAXF, fmaxf(-QMAXF, rintf(v.w / s)));
        q4[i] = q;
    }
}

// ---------------------------------------------------------------------------
// int8 GEMM: C[M,N] = Xq[M,K] . Wq[N,K]^T
// 128x128 tile, 4 waves (64x64 each via 4x4 of 16x16x64 MFMA), BK=128 bytes.
// LDS 2 x 16KB. XOR-swizzled chunk layout: LDS slot (r, cs) holds logical
// chunk cs ^ (r&7), so fragment reads spread uniformly over all 8 bank-groups
// (2 lanes/group = free) instead of 8-way conflicting.
// ---------------------------------------------------------------------------
#define BM 128
#define BN 128
#define BK 128

__global__ __launch_bounds__(256) void gemm_i8_kernel(
    const int8_t* __restrict__ Xq, const int8_t* __restrict__ Wq,
    const float* __restrict__ sxp, const float* __restrict__ s_w,
    const float* __restrict__ bias, float* __restrict__ Y) {
    __shared__ int8_t As[BM * BK];
    __shared__ int8_t Bs[BN * BK];

    const int t = threadIdx.x;
    const int w = t >> 6;
    const int l = t & 63;
    const int lane15 = l & 15;
    const int lquad = l >> 4;
    const int swz = lane15 & 7;
    const int wm = (w >> 1) * 64;
    const int wn = (w & 1) * 64;

    const int bm = blockIdx.y * BM;
    const int bn = blockIdx.x * BN;

    // staging: 1024 chunks of 16B per 16KB tile; thread t owns LDS slots
    // t+256s (s=0..3). Slot cl = (row r = cl>>3, pos cs = cl&7); the data
    // placed there is global chunk cs ^ (r&7)  (XOR swizzle).
    const int8_t* aptr[4];
    const int8_t* bptr[4];
#pragma unroll
    for (int s = 0; s < 4; s++) {
        const int cl = t + 256 * s;
        const int r = cl >> 3;
        const int c = ((cl & 7) ^ (r & 7)) * 16;
        aptr[s] = Xq + (size_t)(bm + r) * Kdim + c;
        bptr[s] = Wq + (size_t)(bn + r) * Kdim + c;
    }
    // wave-uniform LDS bases (HW scatters lane l at base + l*16)
    int8_t* alds[4];
    int8_t* blds[4];
#pragma unroll
    for (int s = 0; s < 4; s++) {
        alds[s] = As + s * 4096 + w * 1024;
        blds[s] = Bs + s * 4096 + w * 1024;
    }

    i32x4 acc[4][4] = {};

    for (int kt = 0; kt < Kdim; kt += BK) {
#pragma unroll
        for (int s = 0; s < 4; s++) async_copy16(aptr[s] + kt, alds[s]);
#pragma unroll
        for (int s = 0; s < 4; s++) async_copy16(bptr[s] + kt, blds[s]);
        __syncthreads();

#pragma unroll
        for (int kk = 0; kk < 2; kk++) {
            i32x4 a[4], b[4];
#pragma unroll
            for (int i = 0; i < 4; i++)
                a[i] = *(const i32x4*)(As + (wm + i * 16 + lane15) * BK +
                                       (((kk << 2) | lquad) ^ swz) * 16);
#pragma unroll
            for (int j = 0; j < 4; j++)
                b[j] = *(const i32x4*)(Bs + (wn + j * 16 + lane15) * BK +
                                       (((kk << 2) | lquad) ^ swz) * 16);
#pragma unroll
            for (int i = 0; i < 4; i++)
#pragma unroll
                for (int j = 0; j < 4; j++)
                    acc[i][j] = __builtin_amdgcn_mfma_i32_16x16x64_i8(
                        a[i], b[j], acc[i][j], 0, 0, 0);
        }
        __syncthreads();
    }

    // epilogue: C/D layout col=lane&15, row=(lane>>4)*4+reg (16x16 shapes)
    const float sx = *sxp;
#pragma unroll
    for (int j = 0; j < 4; j++) {
        const int col = bn + wn + j * 16 + lane15;
        const float sc = sx * s_w[col];
        const float bs = bias[col];
#pragma unroll
        for (int i = 0; i < 4; i++) {
            const int row = bm + wm + i * 16 + lquad * 4;
            float* yp = Y + (size_t)row * Ndim + col;
#pragma unroll
            for (int r = 0; r < 4; r++)
                yp[(size_t)r * Ndim] = (float)acc[i][j][r] * sc + bs;
        }
    }
}

extern "C" void kernel_launch(void* const* d_in, const int* in_sizes, int n_in,
                              void* d_out, int out_size, void* d_ws,
                              size_t ws_size, hipStream_t stream) {
    const float* x = (const float*)d_in[0];
    const int* w_q = (const int*)d_in[1];  // integer inputs arrive as int32
    const float* s_w = (const float*)d_in[2];
    const float* bias = (const float*)d_in[3];
    float* y = (float*)d_out;

    float* sx = (float*)d_ws;                       // [0]      scalar scale
    float* blockmax = (float*)((char*)d_ws + 256);  // [256]    2048 floats
    int8_t* xq = (int8_t*)d_ws + 16384;
    int8_t* wq8 = (int8_t*)d_ws + 16384 + (size_t)Mdim * Kdim;

    prep_kernel<<<PREP_BLOCKS, 256, 0, stream>>>(x, w_q, blockmax, wq8);
    finalize_kernel<<<1, 256, 0, stream>>>(blockmax, sx);
    quant_x_kernel<<<PREP_BLOCKS, 256, 0, stream>>>(x, sx, xq,
                                                    Mdim * Kdim / 4);

    dim3 grid(Ndim / BN, Mdim / BM);
    gemm_i8_kernel<<<grid, 256, 0, stream>>>(xq, wq8, sx, s_w, bias, y);
}